// Round 1
// baseline (14141.872 us; speedup 1.0000x reference)
//
#include <hip/hip_runtime.h>
#include <math.h>

namespace {

constexpr int T_STEPS = 512;
constexpr int IN_DIMC = 64;
constexpr int HIDC    = 128;
constexpr int G4      = 512;   // 4*HID gates per layer
constexpr int ROWS    = 4;     // batch rows per block

__device__ __forceinline__ float dot4(float4 w, float4 v, float a) {
  return fmaf(w.x, v.x, fmaf(w.y, v.y, fmaf(w.z, v.z, fmaf(w.w, v.w, a))));
}

__device__ __forceinline__ float sigmoidf_(float v) {
  return 1.0f / (1.0f + __expf(-v));
}

// 256 blocks x 512 threads. Each block owns ROWS=4 batch rows for the whole
// T-loop; states are block-local (no inter-block traffic). Gate GEMVs are
// split: 256 gate-threads (2 gates each, 4 rows each => 8 accumulators),
// two K-groups (tid<256 / tid>=256) to get 8 waves of parallelism while each
// weight element is still read exactly once per block per step.
__global__ __launch_bounds__(512, 1) void lstm_fused(
    const float* __restrict__ x,     // (B, T, 64)
    const float* __restrict__ Wih0,  // (512, 64)
    const float* __restrict__ Whh0,  // (512, 128)
    const float* __restrict__ b0,    // (512)
    const float* __restrict__ Wih1,  // (512, 128)
    const float* __restrict__ Whh1,  // (512, 128)
    const float* __restrict__ b1,    // (512)
    const float* __restrict__ Wout,  // (1, 128)
    const float* __restrict__ bout,  // (1)
    float* __restrict__ out)         // (B, 1)
{
  const int tid    = threadIdx.x;
  const int blk    = blockIdx.x;
  const int b_base = blk * ROWS;

  __shared__ float xs[ROWS][IN_DIMC];     // current x tile
  __shared__ float hs0[ROWS][HIDC];       // h of layer 0
  __shared__ float hs1[ROWS][HIDC];       // h of layer 1
  __shared__ float zs[2][ROWS][G4];       // partial pre-activations (2 K-groups)

  // cell states held by the owning thread: pair (pr, pu)
  const int pr = tid >> 7;     // 0..3
  const int pu = tid & 127;    // 0..127
  float c0 = 0.f, c1 = 0.f;

  for (int i = tid; i < ROWS * HIDC; i += 512) {
    (&hs0[0][0])[i] = 0.f;
    (&hs1[0][0])[i] = 0.f;
  }
  __syncthreads();

  const int grp = tid >> 8;    // K-group: 0 or 1
  const int gt  = tid & 255;   // gate-thread id
  const int g0  = gt;
  const int g1  = gt + 256;

  // biases for this thread's cell updates (gate order i, f, g, o)
  const float bi0 = b0[pu], bf0 = b0[pu + 128], bg0 = b0[pu + 256], bo0 = b0[pu + 384];
  const float bi1 = b1[pu], bf1 = b1[pu + 128], bg1 = b1[pu + 256], bo1 = b1[pu + 384];

  for (int t = 0; t < T_STEPS; ++t) {
    // ---- stage x_t for this block's rows ----
    if (tid < ROWS * IN_DIMC) {
      int r = tid >> 6, k = tid & 63;
      xs[r][k] = x[((long)(b_base + r) * T_STEPS + t) * IN_DIMC + k];
    }
    __syncthreads();

    // ---- layer 0 gate pre-activations ----
    {
      float a00 = 0.f, a01 = 0.f, a02 = 0.f, a03 = 0.f;
      float a10 = 0.f, a11 = 0.f, a12 = 0.f, a13 = 0.f;
      if (grp == 0) {
        // x @ Wih0^T (K=64) plus Whh0 columns [0,32)
        const float* w0 = Wih0 + g0 * IN_DIMC;
        const float* w1 = Wih0 + g1 * IN_DIMC;
#pragma unroll 8
        for (int k = 0; k < IN_DIMC; k += 4) {
          float4 wa = *(const float4*)(w0 + k);
          float4 wb = *(const float4*)(w1 + k);
          float4 v0 = *(const float4*)&xs[0][k];
          float4 v1 = *(const float4*)&xs[1][k];
          float4 v2 = *(const float4*)&xs[2][k];
          float4 v3 = *(const float4*)&xs[3][k];
          a00 = dot4(wa, v0, a00); a01 = dot4(wa, v1, a01);
          a02 = dot4(wa, v2, a02); a03 = dot4(wa, v3, a03);
          a10 = dot4(wb, v0, a10); a11 = dot4(wb, v1, a11);
          a12 = dot4(wb, v2, a12); a13 = dot4(wb, v3, a13);
        }
        const float* u0 = Whh0 + g0 * HIDC;
        const float* u1 = Whh0 + g1 * HIDC;
#pragma unroll 8
        for (int k = 0; k < 32; k += 4) {
          float4 wa = *(const float4*)(u0 + k);
          float4 wb = *(const float4*)(u1 + k);
          float4 v0 = *(const float4*)&hs0[0][k];
          float4 v1 = *(const float4*)&hs0[1][k];
          float4 v2 = *(const float4*)&hs0[2][k];
          float4 v3 = *(const float4*)&hs0[3][k];
          a00 = dot4(wa, v0, a00); a01 = dot4(wa, v1, a01);
          a02 = dot4(wa, v2, a02); a03 = dot4(wa, v3, a03);
          a10 = dot4(wb, v0, a10); a11 = dot4(wb, v1, a11);
          a12 = dot4(wb, v2, a12); a13 = dot4(wb, v3, a13);
        }
      } else {
        // Whh0 columns [32,128)
        const float* u0 = Whh0 + g0 * HIDC;
        const float* u1 = Whh0 + g1 * HIDC;
#pragma unroll 8
        for (int k = 32; k < HIDC; k += 4) {
          float4 wa = *(const float4*)(u0 + k);
          float4 wb = *(const float4*)(u1 + k);
          float4 v0 = *(const float4*)&hs0[0][k];
          float4 v1 = *(const float4*)&hs0[1][k];
          float4 v2 = *(const float4*)&hs0[2][k];
          float4 v3 = *(const float4*)&hs0[3][k];
          a00 = dot4(wa, v0, a00); a01 = dot4(wa, v1, a01);
          a02 = dot4(wa, v2, a02); a03 = dot4(wa, v3, a03);
          a10 = dot4(wb, v0, a10); a11 = dot4(wb, v1, a11);
          a12 = dot4(wb, v2, a12); a13 = dot4(wb, v3, a13);
        }
      }
      zs[grp][0][g0] = a00; zs[grp][1][g0] = a01;
      zs[grp][2][g0] = a02; zs[grp][3][g0] = a03;
      zs[grp][0][g1] = a10; zs[grp][1][g1] = a11;
      zs[grp][2][g1] = a12; zs[grp][3][g1] = a13;
    }
    __syncthreads();

    // ---- layer 0 cell update ----
    {
      float zi = zs[0][pr][pu]       + zs[1][pr][pu]       + bi0;
      float zf = zs[0][pr][pu + 128] + zs[1][pr][pu + 128] + bf0;
      float zg = zs[0][pr][pu + 256] + zs[1][pr][pu + 256] + bg0;
      float zo = zs[0][pr][pu + 384] + zs[1][pr][pu + 384] + bo0;
      float ct = sigmoidf_(zf) * c0 + sigmoidf_(zi) * tanhf(zg);
      c0 = ct;
      hs0[pr][pu] = sigmoidf_(zo) * tanhf(ct);
    }
    __syncthreads();

    // ---- layer 1 gate pre-activations ----
    {
      float a00 = 0.f, a01 = 0.f, a02 = 0.f, a03 = 0.f;
      float a10 = 0.f, a11 = 0.f, a12 = 0.f, a13 = 0.f;
      // grp 0: h0 @ Wih1^T ; grp 1: h1 @ Whh1^T  (both K=128)
      const float* base = (grp == 0) ? Wih1 : Whh1;
      const float(*hsrc)[HIDC] = (grp == 0) ? hs0 : hs1;
      const float* w0 = base + g0 * HIDC;
      const float* w1 = base + g1 * HIDC;
#pragma unroll 8
      for (int k = 0; k < HIDC; k += 4) {
        float4 wa = *(const float4*)(w0 + k);
        float4 wb = *(const float4*)(w1 + k);
        float4 v0 = *(const float4*)&hsrc[0][k];
        float4 v1 = *(const float4*)&hsrc[1][k];
        float4 v2 = *(const float4*)&hsrc[2][k];
        float4 v3 = *(const float4*)&hsrc[3][k];
        a00 = dot4(wa, v0, a00); a01 = dot4(wa, v1, a01);
        a02 = dot4(wa, v2, a02); a03 = dot4(wa, v3, a03);
        a10 = dot4(wb, v0, a10); a11 = dot4(wb, v1, a11);
        a12 = dot4(wb, v2, a12); a13 = dot4(wb, v3, a13);
      }
      zs[grp][0][g0] = a00; zs[grp][1][g0] = a01;
      zs[grp][2][g0] = a02; zs[grp][3][g0] = a03;
      zs[grp][0][g1] = a10; zs[grp][1][g1] = a11;
      zs[grp][2][g1] = a12; zs[grp][3][g1] = a13;
    }
    __syncthreads();

    // ---- layer 1 cell update ----
    {
      float zi = zs[0][pr][pu]       + zs[1][pr][pu]       + bi1;
      float zf = zs[0][pr][pu + 128] + zs[1][pr][pu + 128] + bf1;
      float zg = zs[0][pr][pu + 256] + zs[1][pr][pu + 256] + bg1;
      float zo = zs[0][pr][pu + 384] + zs[1][pr][pu + 384] + bo1;
      float ct = sigmoidf_(zf) * c1 + sigmoidf_(zi) * tanhf(zg);
      c1 = ct;
      hs1[pr][pu] = sigmoidf_(zo) * tanhf(ct);
    }
    __syncthreads();
  }

  // ---- output projection: y = h1 @ Wout^T + bout ----
  if (tid < ROWS) {
    float acc = bout[0];
#pragma unroll 8
    for (int u = 0; u < HIDC; ++u) acc = fmaf(hs1[tid][u], Wout[u], acc);
    out[b_base + tid] = acc;
  }
}

}  // namespace

extern "C" void kernel_launch(void* const* d_in, const int* in_sizes, int n_in,
                              void* d_out, int out_size, void* d_ws, size_t ws_size,
                              hipStream_t stream) {
  const float* x    = (const float*)d_in[0];
  const float* Wih0 = (const float*)d_in[1];
  const float* Whh0 = (const float*)d_in[2];
  const float* b0   = (const float*)d_in[3];
  const float* Wih1 = (const float*)d_in[4];
  const float* Whh1 = (const float*)d_in[5];
  const float* b1   = (const float*)d_in[6];
  const float* Wout = (const float*)d_in[7];
  const float* bout = (const float*)d_in[8];
  float* out = (float*)d_out;

  lstm_fused<<<dim3(256), dim3(512), 0, stream>>>(
      x, Wih0, Whh0, b0, Wih1, Whh1, b1, Wout, bout, out);
}

// Round 2
// 3930.099 us; speedup vs baseline: 3.5983x; 3.5983x over previous
//
#include <hip/hip_runtime.h>
#include <math.h>

namespace {

constexpr int T_STEPS = 512;
constexpr int IN_DIMC = 64;
constexpr int HIDC    = 128;
constexpr int G4      = 512;   // 4*HID gates per layer
constexpr int ROWS    = 4;     // batch rows per block

typedef _Float16 h2 __attribute__((ext_vector_type(2)));
typedef _Float16 h8 __attribute__((ext_vector_type(8)));

#if __has_builtin(__builtin_amdgcn_fdot2)
__device__ __forceinline__ float fdot2_(h2 a, h2 b, float c) {
  return __builtin_amdgcn_fdot2(a, b, c, false);
}
#else
__device__ __forceinline__ float fdot2_(h2 a, h2 b, float c) {
  return fmaf((float)a.x, (float)b.x, fmaf((float)a.y, (float)b.y, c));
}
#endif

__device__ __forceinline__ float dot8(h8 w, h8 v, float a) {
  a = fdot2_(__builtin_shufflevector(w, w, 0, 1), __builtin_shufflevector(v, v, 0, 1), a);
  a = fdot2_(__builtin_shufflevector(w, w, 2, 3), __builtin_shufflevector(v, v, 2, 3), a);
  a = fdot2_(__builtin_shufflevector(w, w, 4, 5), __builtin_shufflevector(v, v, 4, 5), a);
  a = fdot2_(__builtin_shufflevector(w, w, 6, 7), __builtin_shufflevector(v, v, 6, 7), a);
  return a;
}

__device__ __forceinline__ float sigmoidf_(float v) {
  return 1.0f / (1.0f + __expf(-v));
}

// Pack fp32 weights -> fp16, transposed to [K/8][512 gates][8] so that a
// wave's 64 consecutive-gate lanes read 1KB contiguous per 16B lane-load.
__global__ void pack_weights(const float* __restrict__ Wih0,
                             const float* __restrict__ Whh0,
                             const float* __restrict__ Wih1,
                             const float* __restrict__ Whh1,
                             _Float16* __restrict__ P0, _Float16* __restrict__ P1,
                             _Float16* __restrict__ P2, _Float16* __restrict__ P3) {
  int idx = blockIdx.x * 256 + threadIdx.x;
  if (idx < 32768) {                       // Wih0: (512, 64)
    int g = idx >> 6, k = idx & 63;
    P0[(((k >> 3) << 9) + g) * 8 + (k & 7)] = (_Float16)Wih0[idx];
  } else if (idx < 98304) {                // Whh0: (512, 128)
    int i = idx - 32768;
    int g = i >> 7, k = i & 127;
    P1[(((k >> 3) << 9) + g) * 8 + (k & 7)] = (_Float16)Whh0[i];
  } else if (idx < 163840) {               // Wih1: (512, 128)
    int i = idx - 98304;
    int g = i >> 7, k = i & 127;
    P2[(((k >> 3) << 9) + g) * 8 + (k & 7)] = (_Float16)Wih1[i];
  } else if (idx < 229376) {               // Whh1: (512, 128)
    int i = idx - 163840;
    int g = i >> 7, k = i & 127;
    P3[(((k >> 3) << 9) + g) * 8 + (k & 7)] = (_Float16)Whh1[i];
  }
}

// 256 blocks x 1024 threads (16 waves/CU). Block owns ROWS=4 batch rows.
// Gate GEMVs in fp16 via v_dot2_f32_f16, fp32 accumulate. K split 2 ways:
//   layer0: grp0 = x@Wih0^T (K=64), grp1 = h0@Whh0^T (K=128)
//   layer1: grp0 = h0@Wih1^T (K=128), grp1 = h1@Whh1^T (K=128)
// Cell state c kept fp32 in registers; h stored fp16 in LDS (re-derived from
// fp32 c each step, so h-quantization does not compound).
__global__ __launch_bounds__(1024, 4) void lstm_fused16(
    const float* __restrict__ x,      // (B, T, 64) fp32
    const _Float16* __restrict__ P0,  // Wih0 packed [8][512][8]
    const _Float16* __restrict__ P1,  // Whh0 packed [16][512][8]
    const _Float16* __restrict__ P2,  // Wih1 packed [16][512][8]
    const _Float16* __restrict__ P3,  // Whh1 packed [16][512][8]
    const float* __restrict__ b0,     // (512)
    const float* __restrict__ b1,     // (512)
    const float* __restrict__ Wout,   // (1, 128)
    const float* __restrict__ bout,   // (1)
    float* __restrict__ out)          // (B, 1)
{
  const int tid    = threadIdx.x;
  const int blk    = blockIdx.x;
  const int b_base = blk * ROWS;

  __shared__ float    zs[2][ROWS][G4];   // 16 KB partial pre-activations
  __shared__ _Float16 xs[ROWS][IN_DIMC]; // current x tile (fp16)
  __shared__ _Float16 hs0[ROWS][HIDC];
  __shared__ _Float16 hs1[ROWS][HIDC];

  const int g   = tid & 511;   // gate id (wave lanes are consecutive gates)
  const int grp = tid >> 9;    // K-group (wave-uniform)

  // state threads: tid < 512, pair (pr, pu)
  const int pr = tid >> 7;
  const int pu = tid & 127;
  float c0 = 0.f, c1 = 0.f;
  float bi0 = 0.f, bf0 = 0.f, bg0 = 0.f, bo0 = 0.f;
  float bi1 = 0.f, bf1 = 0.f, bg1 = 0.f, bo1 = 0.f;
  if (tid < 512) {
    hs0[pr][pu] = (_Float16)0.f;
    hs1[pr][pu] = (_Float16)0.f;
    bi0 = b0[pu]; bf0 = b0[pu + 128]; bg0 = b0[pu + 256]; bo0 = b0[pu + 384];
    bi1 = b1[pu]; bf1 = b1[pu + 128]; bg1 = b1[pu + 256]; bo1 = b1[pu + 384];
  }
  __syncthreads();

  const h8* __restrict__ W0 = (const h8*)P0;
  const h8* __restrict__ W1 = (const h8*)P1;
  const h8* __restrict__ W2 = (const h8*)P2;
  const h8* __restrict__ W3 = (const h8*)P3;

  for (int t = 0; t < T_STEPS; ++t) {
    // ---- stage x_t (fp32 -> fp16) ----
    if (tid < ROWS * IN_DIMC) {
      int r = tid >> 6, k = tid & 63;
      xs[r][k] = (_Float16)x[((long)(b_base + r) * T_STEPS + t) * IN_DIMC + k];
    }
    __syncthreads();

    // ---- layer 0 gates ----
    {
      float a0 = 0.f, a1 = 0.f, a2 = 0.f, a3 = 0.f;
      if (grp == 0) {
#pragma unroll
        for (int kb = 0; kb < 8; ++kb) {
          h8 w  = W0[(kb << 9) + g];
          h8 v0 = *(const h8*)&xs[0][kb << 3];
          h8 v1 = *(const h8*)&xs[1][kb << 3];
          h8 v2 = *(const h8*)&xs[2][kb << 3];
          h8 v3 = *(const h8*)&xs[3][kb << 3];
          a0 = dot8(w, v0, a0); a1 = dot8(w, v1, a1);
          a2 = dot8(w, v2, a2); a3 = dot8(w, v3, a3);
        }
      } else {
#pragma unroll 8
        for (int kb = 0; kb < 16; ++kb) {
          h8 w  = W1[(kb << 9) + g];
          h8 v0 = *(const h8*)&hs0[0][kb << 3];
          h8 v1 = *(const h8*)&hs0[1][kb << 3];
          h8 v2 = *(const h8*)&hs0[2][kb << 3];
          h8 v3 = *(const h8*)&hs0[3][kb << 3];
          a0 = dot8(w, v0, a0); a1 = dot8(w, v1, a1);
          a2 = dot8(w, v2, a2); a3 = dot8(w, v3, a3);
        }
      }
      zs[grp][0][g] = a0; zs[grp][1][g] = a1;
      zs[grp][2][g] = a2; zs[grp][3][g] = a3;
    }
    __syncthreads();

    // ---- layer 0 cell update ----
    if (tid < 512) {
      float zi = zs[0][pr][pu]       + zs[1][pr][pu]       + bi0;
      float zf = zs[0][pr][pu + 128] + zs[1][pr][pu + 128] + bf0;
      float zg = zs[0][pr][pu + 256] + zs[1][pr][pu + 256] + bg0;
      float zo = zs[0][pr][pu + 384] + zs[1][pr][pu + 384] + bo0;
      float ct = sigmoidf_(zf) * c0 + sigmoidf_(zi) * tanhf(zg);
      c0 = ct;
      hs0[pr][pu] = (_Float16)(sigmoidf_(zo) * tanhf(ct));
    }
    __syncthreads();

    // ---- layer 1 gates ----
    {
      const h8* __restrict__ W = (grp == 0) ? W2 : W3;
      const _Float16(*hsrc)[HIDC] = (grp == 0) ? hs0 : hs1;
      float a0 = 0.f, a1 = 0.f, a2 = 0.f, a3 = 0.f;
#pragma unroll 8
      for (int kb = 0; kb < 16; ++kb) {
        h8 w  = W[(kb << 9) + g];
        h8 v0 = *(const h8*)&hsrc[0][kb << 3];
        h8 v1 = *(const h8*)&hsrc[1][kb << 3];
        h8 v2 = *(const h8*)&hsrc[2][kb << 3];
        h8 v3 = *(const h8*)&hsrc[3][kb << 3];
        a0 = dot8(w, v0, a0); a1 = dot8(w, v1, a1);
        a2 = dot8(w, v2, a2); a3 = dot8(w, v3, a3);
      }
      zs[grp][0][g] = a0; zs[grp][1][g] = a1;
      zs[grp][2][g] = a2; zs[grp][3][g] = a3;
    }
    __syncthreads();

    // ---- layer 1 cell update ----
    if (tid < 512) {
      float zi = zs[0][pr][pu]       + zs[1][pr][pu]       + bi1;
      float zf = zs[0][pr][pu + 128] + zs[1][pr][pu + 128] + bf1;
      float zg = zs[0][pr][pu + 256] + zs[1][pr][pu + 256] + bg1;
      float zo = zs[0][pr][pu + 384] + zs[1][pr][pu + 384] + bo1;
      float ct = sigmoidf_(zf) * c1 + sigmoidf_(zi) * tanhf(zg);
      c1 = ct;
      hs1[pr][pu] = (_Float16)(sigmoidf_(zo) * tanhf(ct));
    }
    __syncthreads();
  }

  // ---- output projection: y = h1 @ Wout^T + bout ----
  if (tid < ROWS) {
    float acc = bout[0];
#pragma unroll 8
    for (int u = 0; u < HIDC; ++u) acc = fmaf((float)hs1[tid][u], Wout[u], acc);
    out[b_base + tid] = acc;
  }
}

}  // namespace

extern "C" void kernel_launch(void* const* d_in, const int* in_sizes, int n_in,
                              void* d_out, int out_size, void* d_ws, size_t ws_size,
                              hipStream_t stream) {
  const float* x    = (const float*)d_in[0];
  const float* Wih0 = (const float*)d_in[1];
  const float* Whh0 = (const float*)d_in[2];
  const float* b0   = (const float*)d_in[3];
  const float* Wih1 = (const float*)d_in[4];
  const float* Whh1 = (const float*)d_in[5];
  const float* b1   = (const float*)d_in[6];
  const float* Wout = (const float*)d_in[7];
  const float* bout = (const float*)d_in[8];
  float* out = (float*)d_out;

  // fp16 packed weights in workspace (total 448.5 KB)
  _Float16* P0 = (_Float16*)d_ws;                    // 32768 elems
  _Float16* P1 = (_Float16*)((char*)d_ws + 65536);   // 65536 elems
  _Float16* P2 = (_Float16*)((char*)d_ws + 196608);  // 65536 elems
  _Float16* P3 = (_Float16*)((char*)d_ws + 327680);  // 65536 elems

  pack_weights<<<dim3(896), dim3(256), 0, stream>>>(Wih0, Whh0, Wih1, Whh1,
                                                    P0, P1, P2, P3);
  lstm_fused16<<<dim3(256), dim3(1024), 0, stream>>>(
      x, P0, P1, P2, P3, b0, b1, Wout, bout, out);
}